// Round 2
// baseline (202.790 us; speedup 1.0000x reference)
//
#include <hip/hip_runtime.h>
#include <hip/hip_bf16.h>

typedef unsigned long long u64;
typedef unsigned int u32;
typedef unsigned short u16;

#define NB 64
#define NP 2048
#define NT 256
#define TOPK 260
#define EPSF 1e-7f

// K1: cost[t][p] = mean_b (1 - iou(pred[b][p], tgt[b][t]))
__global__ __launch_bounds__(256) void cost_kernel(const float4* __restrict__ pred,
                                                   const float* __restrict__ tgt,
                                                   float* __restrict__ cost) {
    __shared__ float sT[NB][8][4];
    __shared__ float sAreaT[NB][8];
    const int tid = threadIdx.x;
    const int t0 = blockIdx.y * 8;
    const int p = blockIdx.x * 256 + tid;

    // stage this block's 8 target boxes for all 64 batches: 2048 floats
    for (int i = tid; i < NB * 8 * 4; i += 256) {
        int b = i >> 5; int r = i & 31; int tt = r >> 2; int c = r & 3;
        sT[b][tt][c] = tgt[(b * NT + t0 + tt) * 4 + c];
    }
    __syncthreads();
    for (int i = tid; i < NB * 8; i += 256) {
        int b = i >> 3, tt = i & 7;
        sAreaT[b][tt] = (sT[b][tt][2] - sT[b][tt][0]) * (sT[b][tt][3] - sT[b][tt][1]);
    }
    __syncthreads();

    float acc[8];
#pragma unroll
    for (int tt = 0; tt < 8; ++tt) acc[tt] = 0.f;

    for (int b = 0; b < NB; ++b) {
        float4 pb = pred[b * NP + p];
        float ap = (pb.z - pb.x) * (pb.w - pb.y);
#pragma unroll
        for (int tt = 0; tt < 8; ++tt) {
            float tx1 = sT[b][tt][0], ty1 = sT[b][tt][1];
            float tx2 = sT[b][tt][2], ty2 = sT[b][tt][3];
            float ix1 = fmaxf(pb.x, tx1);
            float iy1 = fmaxf(pb.y, ty1);
            float ix2 = fminf(pb.z, tx2);
            float iy2 = fminf(pb.w, ty2);
            float dx = fmaxf(ix2 - ix1, 0.f);
            float dy = fmaxf(iy2 - iy1, 0.f);
            float inter = dx * dy;
            float uni = ap + sAreaT[b][tt] - inter + EPSF;
            float iou = inter / uni;            // IEEE div until we have a PASS baseline
            acc[tt] += (1.f - iou);
        }
    }
#pragma unroll
    for (int tt = 0; tt < 8; ++tt)
        cost[(t0 + tt) * NP + p] = acc[tt] * (1.f / NB);
}

// K2: per-row bitonic sort of (value_bits<<32 | index) keys; emit top-TOPK.
// Key order exactly reproduces jnp.argmin first-occurrence tie-break
// (all costs are finite non-negative -> float bits are order-isomorphic).
__global__ __launch_bounds__(256) void sort_kernel(const float* __restrict__ cost,
                                                   u64* __restrict__ toplist) {
    __shared__ u64 s[NP];
    const int tid = threadIdx.x;
    const int t = blockIdx.x;
    for (int i = tid; i < NP; i += 256) {
        u32 vb = __float_as_uint(cost[t * NP + i]);
        s[i] = ((u64)vb << 32) | (u32)i;
    }
    __syncthreads();
    for (int k = 2; k <= NP; k <<= 1) {
        for (int j = k >> 1; j > 0; j >>= 1) {
            for (int i = tid; i < NP; i += 256) {
                int ixj = i ^ j;
                if (ixj > i) {
                    u64 a = s[i], b = s[ixj];
                    bool up = ((i & k) == 0);
                    if ((a > b) == up) { s[i] = b; s[ixj] = a; }
                }
            }
            __syncthreads();
        }
    }
    for (int i = tid; i < TOPK; i += 256) toplist[t * TOPK + i] = s[i];
}

// K3: serial greedy over 256 rows, one wave. Lane l inspects sorted
// candidate l; ballot finds first unmasked. At step t exactly t preds are
// masked, so the answer is always within the first t+1 <= 256 <= TOPK
// sorted candidates; lanes cover 0..63, fallback covers 64..TOPK-1.
// LDS: 64KB vals + 32KB idxs + 2KB mask = 98 KB (safely under limits).
__global__ __launch_bounds__(64) void greedy_kernel(const u64* __restrict__ toplist,
                                                    float* __restrict__ out) {
    __shared__ float sv[NT][64];
    __shared__ u16 si[NT][64];
    __shared__ unsigned char mask[NP];
    const int lane = threadIdx.x;
    for (int i = lane; i < NT * 64; i += 64) {
        int t = i >> 6, l = i & 63;
        u64 k = toplist[t * TOPK + l];
        sv[t][l] = __uint_as_float((u32)(k >> 32));
        si[t][l] = (u16)(k & 0xFFFFu);
    }
    for (int i = lane; i < NP; i += 64) mask[i] = 0;
    __syncthreads();

    float sum = 0.f;
    for (int t = 0; t < NT; ++t) {
        float v = sv[t][lane];
        int idx = (int)si[t][lane];
        bool avail = (mask[idx] == 0);
        u64 bal = __ballot(avail);
        float val;
        int pick;
        if (bal != 0) {
            int f = (int)__ffsll((long long)bal) - 1;
            val = __shfl(v, f);
            pick = __shfl(idx, f);
        } else {
            // rare: all of the first 64 candidates masked -> scan the rest
            u32 vb = 0; int pi = 0;
            if (lane == 0) {
                for (int j = 64; j < TOPK; ++j) {
                    u64 kj = toplist[t * TOPK + j];
                    int ij = (int)(kj & 0xFFFFu);
                    if (mask[ij] == 0) { vb = (u32)(kj >> 32); pi = ij; break; }
                }
            }
            val = __uint_as_float((u32)__shfl((int)vb, 0));
            pick = __shfl(pi, 0);
        }
        sum += val;
        if (lane == 0) mask[pick] = 1;
        __syncthreads();  // make mask write visible before next iteration
    }
    if (lane == 0) out[0] = sum * (1.f / NT);
}

extern "C" void kernel_launch(void* const* d_in, const int* in_sizes, int n_in,
                              void* d_out, int out_size, void* d_ws, size_t ws_size,
                              hipStream_t stream) {
    const float4* pred = (const float4*)d_in[0];
    const float* tgt = (const float*)d_in[1];
    float* cost = (float*)d_ws;
    u64* toplist = (u64*)((char*)d_ws + (size_t)NT * NP * sizeof(float));

    dim3 g1(NP / 256, NT / 8);
    cost_kernel<<<g1, 256, 0, stream>>>(pred, tgt, cost);
    sort_kernel<<<NT, 256, 0, stream>>>(cost, toplist);
    greedy_kernel<<<1, 64, 0, stream>>>(toplist, (float*)d_out);
}

// Round 3
// 100.759 us; speedup vs baseline: 2.0126x; 2.0126x over previous
//
#include <hip/hip_runtime.h>
#include <hip/hip_bf16.h>

typedef unsigned long long u64;
typedef unsigned int u32;

#define NB 64
#define NP 2048
#define NT 256
#define NC 256      // candidates kept per row (rank 0..255 covers worst case t=255)
#define W 8         // greedy window
#define EPSF 1e-7f

// K1: cost[t][p] = mean_b (1 - iou(pred[b][p], tgt[b][t]))
// Target reads are wave-uniform -> scalar loads; fast rcp instead of IEEE div.
__global__ __launch_bounds__(256) void cost_kernel(const float4* __restrict__ pred,
                                                   const float* __restrict__ tgt,
                                                   float* __restrict__ cost) {
    const int tid = threadIdx.x;
    const int t0 = blockIdx.y * 8;
    const int p = blockIdx.x * 256 + tid;

    float acc[8];
#pragma unroll
    for (int tt = 0; tt < 8; ++tt) acc[tt] = 0.f;

    for (int b = 0; b < NB; ++b) {
        float4 pb = pred[b * NP + p];
        float ap = (pb.z - pb.x) * (pb.w - pb.y);
#pragma unroll
        for (int tt = 0; tt < 8; ++tt) {
            const float* tb = &tgt[(b * NT + t0 + tt) * 4];  // uniform -> s_load
            float tx1 = tb[0], ty1 = tb[1], tx2 = tb[2], ty2 = tb[3];
            float at = (tx2 - tx1) * (ty2 - ty1);
            float ix1 = fmaxf(pb.x, tx1);
            float iy1 = fmaxf(pb.y, ty1);
            float ix2 = fminf(pb.z, tx2);
            float iy2 = fminf(pb.w, ty2);
            float dx = fmaxf(ix2 - ix1, 0.f);
            float dy = fmaxf(iy2 - iy1, 0.f);
            float inter = dx * dy;
            float uni = ap + at - inter + EPSF;
            float iou = inter * __builtin_amdgcn_rcpf(uni);
            acc[tt] += (1.f - iou);
        }
    }
#pragma unroll
    for (int tt = 0; tt < 8; ++tt)
        cost[(t0 + tt) * NP + p] = acc[tt] * (1.f / NB);
}

// K2: per-row bitonic sort of (value_bits<<32 | index); emit sorted top-NC.
// Each sub-phase: every thread owns 4 disjoint pairs. All reads batched
// before any write (no intra-phase hazard: each element belongs to exactly
// one pair), so the compiler can issue the 8 ds_read_b64 together.
__global__ __launch_bounds__(256) void sort_kernel(const float* __restrict__ cost,
                                                   u64* __restrict__ toplist) {
    __shared__ u64 s[NP];
    const int tid = threadIdx.x;
    const int t = blockIdx.x;
    for (int i = tid; i < NP; i += 256) {
        u32 vb = __float_as_uint(cost[t * NP + i]);
        s[i] = ((u64)vb << 32) | (u32)i;
    }
    __syncthreads();
    for (int k = 2; k <= NP; k <<= 1) {
        for (int j = k >> 1; j > 0; j >>= 1) {
            u64 a[4], b[4];
            int ia[4], ib[4];
            bool up[4];
#pragma unroll
            for (int m = 0; m < 4; ++m) {
                int pr = tid + 256 * m;                      // pair id 0..1023
                int i = ((pr & ~(j - 1)) << 1) | (pr & (j - 1));
                ia[m] = i; ib[m] = i | j;
                up[m] = ((i & k) == 0);
                a[m] = s[i];
                b[m] = s[i | j];
            }
#pragma unroll
            for (int m = 0; m < 4; ++m) {
                bool lt = a[m] < b[m];
                u64 lo = lt ? a[m] : b[m];
                u64 hi = lt ? b[m] : a[m];
                s[ia[m]] = up[m] ? lo : hi;
                s[ib[m]] = up[m] ? hi : lo;
            }
            __syncthreads();
        }
    }
    if (tid < NC) toplist[t * NC + tid] = s[tid];
}

// K3: serial greedy, one wave, W-row windows, ZERO LDS / ZERO barriers.
// Mask in registers: lane l owns bits for idx in [32l, 32l+32) (u32 m).
// Query = one ds_bpermute gather; pick broadcast = readlane (scalar).
// At step t the pick is within the first t+1 <= 256 sorted candidates:
// lanes cover rank 0..63, fallback chunks cover 64..255.
__global__ __launch_bounds__(64) void greedy_kernel(const u64* __restrict__ toplist,
                                                    float* __restrict__ out) {
    const int lane = threadIdx.x;
    u32 m = 0;          // my 32 mask bits
    float sum = 0.f;    // uniform across lanes (picks are uniform)

    u64 cur[W], nxt[W];
#pragma unroll
    for (int w = 0; w < W; ++w) cur[w] = toplist[w * NC + lane];

    for (int t0 = 0; t0 < NT; t0 += W) {
        // prefetch next window (L2-resident; hides under this window's chain)
#pragma unroll
        for (int w = 0; w < W; ++w) {
            int tn = t0 + W + w;
            nxt[w] = toplist[(tn < NT ? tn : NT - 1) * NC + lane];
        }
        // gather availability for all W rows under the current mask
        bool avail[W]; u32 idx[W]; u32 vb[W];
#pragma unroll
        for (int w = 0; w < W; ++w) {
            idx[w] = (u32)cur[w] & (NP - 1);
            vb[w]  = (u32)(cur[w] >> 32);
            int word = __builtin_amdgcn_ds_bpermute((int)((idx[w] >> 5) << 2), (int)m);
            avail[w] = (((u32)word >> (idx[w] & 31)) & 1u) == 0u;
        }
        // serial resolution
#pragma unroll
        for (int w = 0; w < W; ++w) {
            u64 bal = __ballot(avail[w]);
            u32 pickIdx; float pickVal;
            if (bal != 0) {                               // uniform branch
                int f = (int)__ffsll((unsigned long long)bal) - 1;
                pickIdx = (u32)__builtin_amdgcn_readlane((int)idx[w], f);
                pickVal = __uint_as_float((u32)__builtin_amdgcn_readlane((int)vb[w], f));
            } else {
                // rare: first 64 candidates all taken -> deeper chunks, fresh mask
                pickIdx = 0; pickVal = 0.f;
                bool done = false;
                for (int c = 1; c < 4 && !done; ++c) {
                    u64 key = toplist[(t0 + w) * NC + c * 64 + lane];
                    u32 fi = (u32)key & (NP - 1);
                    int wrd = __builtin_amdgcn_ds_bpermute((int)((fi >> 5) << 2), (int)m);
                    bool av = (((u32)wrd >> (fi & 31)) & 1u) == 0u;
                    u64 b2 = __ballot(av);
                    if (b2 != 0) {
                        int f2 = (int)__ffsll((unsigned long long)b2) - 1;
                        pickIdx = (u32)__builtin_amdgcn_readlane((int)fi, f2);
                        pickVal = __uint_as_float(
                            (u32)__builtin_amdgcn_readlane((int)(u32)(key >> 32), f2));
                        done = true;
                    }
                }
            }
            sum += pickVal;
            // immediate mask update (keeps fallback gathers exact)
            if ((pickIdx >> 5) == (u32)lane) m |= (1u << (pickIdx & 31));
            // in-window exclusion for later rows (their gather is stale)
#pragma unroll
            for (int w2 = w + 1; w2 < W; ++w2)
                avail[w2] = avail[w2] && (idx[w2] != pickIdx);
        }
#pragma unroll
        for (int w = 0; w < W; ++w) cur[w] = nxt[w];
    }
    if (lane == 0) out[0] = sum * (1.f / NT);
}

extern "C" void kernel_launch(void* const* d_in, const int* in_sizes, int n_in,
                              void* d_out, int out_size, void* d_ws, size_t ws_size,
                              hipStream_t stream) {
    const float4* pred = (const float4*)d_in[0];
    const float* tgt = (const float*)d_in[1];
    float* cost = (float*)d_ws;
    u64* toplist = (u64*)((char*)d_ws + (size_t)NT * NP * sizeof(float));

    dim3 g1(NP / 256, NT / 8);
    cost_kernel<<<g1, 256, 0, stream>>>(pred, tgt, cost);
    sort_kernel<<<NT, 256, 0, stream>>>(cost, toplist);
    greedy_kernel<<<1, 64, 0, stream>>>(toplist, (float*)d_out);
}

// Round 4
// 88.062 us; speedup vs baseline: 2.3028x; 1.1442x over previous
//
#include <hip/hip_runtime.h>
#include <hip/hip_bf16.h>

typedef unsigned long long u64;
typedef unsigned int u32;

#define NB 64
#define NP 2048
#define NT 256
#define TK 16       // sorted top-K kept per row
#define EPSF 1e-7f

// K1: cost[t][p] = mean_b (1 - iou). 4 targets/block, grid (8,64) = 512 blocks.
// Target reads are wave-uniform -> s_load; fast rcp (validated: absmax 0.0).
__global__ __launch_bounds__(256) void cost_kernel(const float4* __restrict__ pred,
                                                   const float* __restrict__ tgt,
                                                   float* __restrict__ cost) {
    const int tid = threadIdx.x;
    const int t0 = blockIdx.y * 4;
    const int p = blockIdx.x * 256 + tid;

    float acc[4];
#pragma unroll
    for (int tt = 0; tt < 4; ++tt) acc[tt] = 0.f;

#pragma unroll 2
    for (int b = 0; b < NB; ++b) {
        float4 pb = pred[b * NP + p];
        float ap = (pb.z - pb.x) * (pb.w - pb.y);
#pragma unroll
        for (int tt = 0; tt < 4; ++tt) {
            const float* tb = &tgt[(b * NT + t0 + tt) * 4];  // uniform -> s_load
            float tx1 = tb[0], ty1 = tb[1], tx2 = tb[2], ty2 = tb[3];
            float at = (tx2 - tx1) * (ty2 - ty1);
            float ix1 = fmaxf(pb.x, tx1);
            float iy1 = fmaxf(pb.y, ty1);
            float ix2 = fminf(pb.z, tx2);
            float iy2 = fminf(pb.w, ty2);
            float dx = fmaxf(ix2 - ix1, 0.f);
            float dy = fmaxf(iy2 - iy1, 0.f);
            float inter = dx * dy;
            float uni = ap + at - inter + EPSF;
            acc[tt] += (1.f - inter * __builtin_amdgcn_rcpf(uni));
        }
    }
#pragma unroll
    for (int tt = 0; tt < 4; ++tt)
        cost[(t0 + tt) * NP + p] = acc[tt] * (1.f / NB);
}

__device__ inline u64 wave_min_u64(u64 k) {
#pragma unroll
    for (int off = 1; off < 64; off <<= 1) {
        u32 lo = (u32)__shfl_xor((int)(u32)k, off);
        u32 hi = (u32)__shfl_xor((int)(u32)(k >> 32), off);
        u64 o = ((u64)hi << 32) | lo;
        if (o < k) k = o;
    }
    return k;  // uniform across lanes
}

// K2: one wave per row; sorted top-16 by repeated extraction on packed
// (valbits<<32 | idx) keys. Exactly reproduces argmin first-occurrence order.
// Zero LDS, zero barriers. Slot s=4k+e holds global idx k*256 + 4*lane + e
// (ascending in s for fixed lane -> packed key handles all tie-breaks).
__global__ __launch_bounds__(64) void topk_kernel(const float* __restrict__ cost,
                                                  u64* __restrict__ toplist) {
    const int lane = threadIdx.x;
    const int t = blockIdx.x;
    const float* row = cost + (size_t)t * NP;

    float v[32];
#pragma unroll
    for (int k = 0; k < 8; ++k) {
        float4 q = *(const float4*)(row + k * 256 + 4 * lane);
        v[4 * k + 0] = q.x; v[4 * k + 1] = q.y;
        v[4 * k + 2] = q.z; v[4 * k + 3] = q.w;
    }
    const u32 base = 4u * (u32)lane;
    u32 used = 0;
    for (int e = 0; e < TK; ++e) {
        u64 best = ~0ull;
        u32 bs = 0;
#pragma unroll
        for (int s = 0; s < 32; ++s) {
            u32 hb = ((used >> s) & 1u) ? 0xFFFFFFFFu : __float_as_uint(v[s]);
            u32 gidx = (u32)((s >> 2) * 256) + base + (u32)(s & 3);
            u64 key = ((u64)hb << 32) | gidx;
            if (key < best) { best = key; bs = (u32)s; }
        }
        u64 g = wave_min_u64(best);
        if (best == g) used |= (1u << bs);   // unique winner (idx in key)
        if (lane == 0) toplist[t * TK + e] = g;
    }
}

// cold path: exact masked argmin over the full cost row (first-occurrence)
__device__ void fallback_pick(const float* __restrict__ row, u32 m, int lane,
                              u32* pickIdx, float* pickVal) {
    u64 best = ~0ull;
#pragma unroll 1
    for (int k = 0; k < 8; ++k) {
        float4 q = *(const float4*)(row + k * 256 + 4 * lane);
        float vv[4] = {q.x, q.y, q.z, q.w};
#pragma unroll
        for (int e = 0; e < 4; ++e) {
            u32 gidx = (u32)(k * 256 + 4 * lane + e);
            int w = __builtin_amdgcn_ds_bpermute((int)((gidx >> 5) << 2), (int)m);
            bool taken = (((u32)w >> (gidx & 31)) & 1u) != 0u;
            u32 hb = taken ? 0xFFFFFFFFu : __float_as_uint(vv[e]);
            u64 key = ((u64)hb << 32) | gidx;
            if (key < best) best = key;
        }
    }
    best = wave_min_u64(best);
    *pickIdx = (u32)best & (NP - 1);
    *pickVal = __uint_as_float((u32)(best >> 32));
}

// K3: serial greedy, one wave, 4 rows per ballot batch (16 candidates each).
// Mask in registers: lane l owns bits for preds [32l, 32l+32).
// One bpermute gather per 4 rows; in-batch staleness fixed by idx compares.
__global__ __launch_bounds__(64) void greedy_kernel(const u64* __restrict__ toplist,
                                                    const float* __restrict__ cost,
                                                    float* __restrict__ out) {
    const int lane = threadIdx.x;
    const int g = lane >> 4;    // row-in-batch 0..3
    const int c = lane & 15;    // candidate rank 0..15
    u32 m = 0;
    float sum = 0.f;

    u64 cur = toplist[g * TK + c];
    for (int t0 = 0; t0 < NT; t0 += 4) {
        u64 nxt = 0;
        if (t0 + 4 < NT) nxt = toplist[(t0 + 4 + g) * TK + c];

        u32 idx = (u32)cur & (NP - 1);
        u32 vb = (u32)(cur >> 32);
        int w = __builtin_amdgcn_ds_bpermute((int)((idx >> 5) << 2), (int)m);
        bool avail = (((u32)w >> (idx & 31)) & 1u) == 0u;

#pragma unroll
        for (int gg = 0; gg < 4; ++gg) {
            u64 bal = __ballot(avail && (g == gg));
            u32 pickIdx; float pickVal;
            if (bal != 0) {                       // uniform branch
                int f = (int)__ffsll(bal) - 1;    // lowest lane = lowest rank
                pickIdx = (u32)__builtin_amdgcn_readlane((int)idx, f);
                pickVal = __uint_as_float((u32)__builtin_amdgcn_readlane((int)vb, f));
            } else {
                fallback_pick(cost + (size_t)(t0 + gg) * NP, m, lane,
                              &pickIdx, &pickVal);
            }
            sum += pickVal;
            if ((pickIdx >> 5) == (u32)lane) m |= (1u << (pickIdx & 31));
            avail = avail && (idx != pickIdx);    // exclusion for later rows
        }
        cur = nxt;
    }
    if (lane == 0) out[0] = sum * (1.f / NT);
}

extern "C" void kernel_launch(void* const* d_in, const int* in_sizes, int n_in,
                              void* d_out, int out_size, void* d_ws, size_t ws_size,
                              hipStream_t stream) {
    const float4* pred = (const float4*)d_in[0];
    const float* tgt = (const float*)d_in[1];
    float* cost = (float*)d_ws;
    u64* toplist = (u64*)((char*)d_ws + (size_t)NT * NP * sizeof(float));

    cost_kernel<<<dim3(NP / 256, NT / 4), 256, 0, stream>>>(pred, tgt, cost);
    topk_kernel<<<NT, 64, 0, stream>>>(cost, toplist);
    greedy_kernel<<<1, 64, 0, stream>>>(toplist, cost, (float*)d_out);
}

// Round 5
// 75.275 us; speedup vs baseline: 2.6940x; 1.1699x over previous
//
#include <hip/hip_runtime.h>
#include <hip/hip_bf16.h>

typedef unsigned long long u64;
typedef unsigned int u32;

#define NB 64
#define NP 2048
#define NT 256
#define TK 8        // sorted top-K kept per row
#define RB 8        // rows resolved per greedy batch (RB*TK = 64 lanes)
#define EPSF 1e-7f

// K1: cost[t][p] = mean_b (1 - iou). 4 targets/block, grid (8,64) = 512 blocks.
// b-loop unrolled x4 with grouped loads: 4 float4 VMEM + 4x64B tgt s_loads in
// flight while previous group computes. rcp validated exact-enough (absmax 0).
__global__ __launch_bounds__(256) void cost_kernel(const float4* __restrict__ pred,
                                                   const float* __restrict__ tgt,
                                                   float* __restrict__ cost) {
    const int tid = threadIdx.x;
    const int t0 = blockIdx.y * 4;
    const int p = blockIdx.x * 256 + tid;

    float acc[4] = {0.f, 0.f, 0.f, 0.f};

    for (int b = 0; b < NB; b += 4) {
        float4 pb[4];
#pragma unroll
        for (int u = 0; u < 4; ++u) pb[u] = pred[(b + u) * NP + p];
#pragma unroll
        for (int u = 0; u < 4; ++u) {
            float ap = (pb[u].z - pb[u].x) * (pb[u].w - pb[u].y);
            const float* tb = &tgt[((b + u) * NT + t0) * 4];  // uniform -> s_load x16
#pragma unroll
            for (int tt = 0; tt < 4; ++tt) {
                float tx1 = tb[4 * tt + 0], ty1 = tb[4 * tt + 1];
                float tx2 = tb[4 * tt + 2], ty2 = tb[4 * tt + 3];
                float at = (tx2 - tx1) * (ty2 - ty1);
                float ix1 = fmaxf(pb[u].x, tx1);
                float iy1 = fmaxf(pb[u].y, ty1);
                float ix2 = fminf(pb[u].z, tx2);
                float iy2 = fminf(pb[u].w, ty2);
                float dx = fmaxf(ix2 - ix1, 0.f);
                float dy = fmaxf(iy2 - iy1, 0.f);
                float inter = dx * dy;
                float uni = ap + at - inter + EPSF;
                acc[tt] += (1.f - inter * __builtin_amdgcn_rcpf(uni));
            }
        }
    }
#pragma unroll
    for (int tt = 0; tt < 4; ++tt)
        cost[(t0 + tt) * NP + p] = acc[tt] * (1.f / NB);
}

__device__ inline u64 wave_min_u64(u64 k) {
#pragma unroll
    for (int off = 1; off < 64; off <<= 1) {
        u32 lo = (u32)__shfl_xor((int)(u32)k, off);
        u32 hi = (u32)__shfl_xor((int)(u32)(k >> 32), off);
        u64 o = ((u64)hi << 32) | lo;
        if (o < k) k = o;
    }
    return k;  // uniform across lanes
}

// K2: one wave per row; sorted top-8 by repeated extraction on packed
// (valbits<<32 | idx) keys. Exactly reproduces argmin first-occurrence order.
__global__ __launch_bounds__(64) void topk_kernel(const float* __restrict__ cost,
                                                  u64* __restrict__ toplist) {
    const int lane = threadIdx.x;
    const int t = blockIdx.x;
    const float* row = cost + (size_t)t * NP;

    float v[32];
#pragma unroll
    for (int k = 0; k < 8; ++k) {
        float4 q = *(const float4*)(row + k * 256 + 4 * lane);
        v[4 * k + 0] = q.x; v[4 * k + 1] = q.y;
        v[4 * k + 2] = q.z; v[4 * k + 3] = q.w;
    }
    const u32 base = 4u * (u32)lane;
    u32 used = 0;
    for (int e = 0; e < TK; ++e) {
        u64 best = ~0ull;
        u32 bs = 0;
#pragma unroll
        for (int s = 0; s < 32; ++s) {
            u32 hb = ((used >> s) & 1u) ? 0xFFFFFFFFu : __float_as_uint(v[s]);
            u32 gidx = (u32)((s >> 2) * 256) + base + (u32)(s & 3);
            u64 key = ((u64)hb << 32) | gidx;
            if (key < best) { best = key; bs = (u32)s; }
        }
        u64 g = wave_min_u64(best);
        if (best == g) used |= (1u << bs);   // unique winner (idx in key)
        if (lane == 0) toplist[t * TK + e] = g;
    }
}

// cold path: exact masked argmin over the full cost row (first-occurrence)
__device__ void fallback_pick(const float* __restrict__ row, u32 m, int lane,
                              u32* pickIdx, float* pickVal) {
    u64 best = ~0ull;
#pragma unroll 1
    for (int k = 0; k < 8; ++k) {
        float4 q = *(const float4*)(row + k * 256 + 4 * lane);
        float vv[4] = {q.x, q.y, q.z, q.w};
#pragma unroll
        for (int e = 0; e < 4; ++e) {
            u32 gidx = (u32)(k * 256 + 4 * lane + e);
            int w = __builtin_amdgcn_ds_bpermute((int)((gidx >> 5) << 2), (int)m);
            bool taken = (((u32)w >> (gidx & 31)) & 1u) != 0u;
            u32 hb = taken ? 0xFFFFFFFFu : __float_as_uint(vv[e]);
            u64 key = ((u64)hb << 32) | gidx;
            if (key < best) best = key;
        }
    }
    best = wave_min_u64(best);
    *pickIdx = (u32)best & (NP - 1);
    *pickVal = __uint_as_float((u32)(best >> 32));
}

// K3: serial greedy, one wave. Lane = g*8+c: row-in-batch g (0..7), rank c
// (0..7). Availability word A (64-bit SGPR) computed ONCE per batch; per pick:
// s_and byte-select -> s_ff1 -> readlane idx/val -> v_cmp dup-clear. Next
// batch's toplist load + bpermute issued before resolution (latency hidden);
// its word repaired afterwards against this batch's 8 picks.
// Mask in registers: lane l owns preds [32l, 32l+32).
__global__ __launch_bounds__(64) void greedy_kernel(const u64* __restrict__ toplist,
                                                    const float* __restrict__ cost,
                                                    float* __restrict__ out) {
    const int lane = threadIdx.x;
    const int g = lane >> 3;
    const int c = lane & 7;
    u32 m = 0;
    float sum = 0.f;

    // batch 0: load + gather (m=0 -> all available)
    u64 cur = toplist[g * TK + c];
    u32 idx = (u32)cur & (NP - 1);
    u32 vb = (u32)(cur >> 32);
    u64 A = ~0ull;

    for (int t0 = 0; t0 < NT; t0 += RB) {
        const bool have_next = (t0 + RB < NT);
        u32 idxn = 0, vbn = 0;
        int wn = 0;
        if (have_next) {
            u64 nk = toplist[(t0 + RB + g) * TK + c];
            idxn = (u32)nk & (NP - 1);
            vbn = (u32)(nk >> 32);
            wn = __builtin_amdgcn_ds_bpermute((int)((idxn >> 5) << 2), (int)m);
        }

        u32 pk[RB];
#pragma unroll
        for (int gg = 0; gg < RB; ++gg) {
            u64 bal = A & (0xFFull << (8 * gg));
            u32 pickIdx; float pickVal;
            if (bal != 0) {                          // uniform branch
                int f = (int)__ffsll(bal) - 1;       // lowest lane = lowest rank
                pickIdx = (u32)__builtin_amdgcn_readlane((int)idx, f);
                pickVal = __uint_as_float((u32)__builtin_amdgcn_readlane((int)vb, f));
            } else {
                fallback_pick(cost + (size_t)(t0 + gg) * NP, m, lane,
                              &pickIdx, &pickVal);
            }
            pk[gg] = pickIdx;
            sum += pickVal;
            if ((pickIdx >> 5) == (u32)lane) m |= (1u << (pickIdx & 31));
            A &= ~__ballot(idx == pickIdx);          // clear pick + in-batch dups
        }

        if (have_next) {
            // availability of next batch under pre-batch mask, then repair
            // against this batch's picks (the only staleness).
            u64 An = __ballot((((u32)wn >> (idxn & 31)) & 1u) == 0u);
#pragma unroll
            for (int gg = 0; gg < RB; ++gg)
                An &= ~__ballot(idxn == pk[gg]);
            A = An;
            idx = idxn;
            vb = vbn;
        }
    }
    if (lane == 0) out[0] = sum * (1.f / NT);
}

extern "C" void kernel_launch(void* const* d_in, const int* in_sizes, int n_in,
                              void* d_out, int out_size, void* d_ws, size_t ws_size,
                              hipStream_t stream) {
    const float4* pred = (const float4*)d_in[0];
    const float* tgt = (const float*)d_in[1];
    float* cost = (float*)d_ws;
    u64* toplist = (u64*)((char*)d_ws + (size_t)NT * NP * sizeof(float));

    cost_kernel<<<dim3(NP / 256, NT / 4), 256, 0, stream>>>(pred, tgt, cost);
    topk_kernel<<<NT, 64, 0, stream>>>(cost, toplist);
    greedy_kernel<<<1, 64, 0, stream>>>(toplist, cost, (float*)d_out);
}

// Round 6
// 69.628 us; speedup vs baseline: 2.9125x; 1.0811x over previous
//
#include <hip/hip_runtime.h>
#include <hip/hip_bf16.h>

typedef unsigned long long u64;
typedef unsigned int u32;

#define NB 64
#define NP 2048
#define NT 256
#define TK 8        // sorted top-K kept per row
#define RB 8        // rows resolved per greedy batch (RB*TK = 64 lanes)
#define NZ 4        // batch-dimension split of cost kernel
#define BZ (NB / NZ)
#define EPSF 1e-7f

// K1: partial[z][t][p] = sum_{b in chunk z} (1 - iou(pred[b][p], tgt[b][t]))
// grid (8, 64, 4) = 2048 blocks -> 8 blocks/CU, 32 waves/CU (latency hidden).
__global__ __launch_bounds__(256) void cost_kernel(const float4* __restrict__ pred,
                                                   const float* __restrict__ tgt,
                                                   float* __restrict__ partial) {
    const int tid = threadIdx.x;
    const int t0 = blockIdx.y * 4;
    const int z = blockIdx.z;
    const int p = blockIdx.x * 256 + tid;

    float acc[4] = {0.f, 0.f, 0.f, 0.f};

    for (int b = z * BZ; b < z * BZ + BZ; b += 4) {
        float4 pb[4];
#pragma unroll
        for (int u = 0; u < 4; ++u) pb[u] = pred[(b + u) * NP + p];
#pragma unroll
        for (int u = 0; u < 4; ++u) {
            float ap = (pb[u].z - pb[u].x) * (pb[u].w - pb[u].y);
            const float* tb = &tgt[((b + u) * NT + t0) * 4];  // uniform -> s_load
#pragma unroll
            for (int tt = 0; tt < 4; ++tt) {
                float tx1 = tb[4 * tt + 0], ty1 = tb[4 * tt + 1];
                float tx2 = tb[4 * tt + 2], ty2 = tb[4 * tt + 3];
                float at = (tx2 - tx1) * (ty2 - ty1);
                float ix1 = fmaxf(pb[u].x, tx1);
                float iy1 = fmaxf(pb[u].y, ty1);
                float ix2 = fminf(pb[u].z, tx2);
                float iy2 = fminf(pb[u].w, ty2);
                float dx = fmaxf(ix2 - ix1, 0.f);
                float dy = fmaxf(iy2 - iy1, 0.f);
                float inter = dx * dy;
                float uni = ap + at - inter + EPSF;
                acc[tt] += (1.f - inter * __builtin_amdgcn_rcpf(uni));
            }
        }
    }
#pragma unroll
    for (int tt = 0; tt < 4; ++tt)
        partial[((size_t)z * NT + t0 + tt) * NP + p] = acc[tt];
}

__device__ inline u64 wave_min_u64(u64 k) {
#pragma unroll
    for (int off = 1; off < 64; off <<= 1) {
        u32 lo = (u32)__shfl_xor((int)(u32)k, off);
        u32 hi = (u32)__shfl_xor((int)(u32)(k >> 32), off);
        u64 o = ((u64)hi << 32) | lo;
        if (o < k) k = o;
    }
    return k;  // uniform across lanes
}

// K2: fused 4-way partial reduce + cost-row write + sorted top-8 extraction.
// One wave per row; packed (valbits<<32 | idx) keys reproduce argmin
// first-occurrence tie-break exactly. Zero LDS, zero barriers.
__global__ __launch_bounds__(64) void topk_kernel(const float* __restrict__ partial,
                                                  float* __restrict__ cost,
                                                  u64* __restrict__ toplist) {
    const int lane = threadIdx.x;
    const int t = blockIdx.x;
    const float* r0 = partial + ((size_t)0 * NT + t) * NP;
    const float* r1 = partial + ((size_t)1 * NT + t) * NP;
    const float* r2 = partial + ((size_t)2 * NT + t) * NP;
    const float* r3 = partial + ((size_t)3 * NT + t) * NP;
    float* crow = cost + (size_t)t * NP;

    float v[32];
#pragma unroll
    for (int k = 0; k < 8; ++k) {
        const int off = k * 256 + 4 * lane;
        float4 a = *(const float4*)(r0 + off);
        float4 b = *(const float4*)(r1 + off);
        float4 c = *(const float4*)(r2 + off);
        float4 d = *(const float4*)(r3 + off);
        float4 s;
        s.x = (a.x + b.x + c.x + d.x) * (1.f / NB);
        s.y = (a.y + b.y + c.y + d.y) * (1.f / NB);
        s.z = (a.z + b.z + c.z + d.z) * (1.f / NB);
        s.w = (a.w + b.w + c.w + d.w) * (1.f / NB);
        *(float4*)(crow + off) = s;   // greedy fallback reads this
        v[4 * k + 0] = s.x; v[4 * k + 1] = s.y;
        v[4 * k + 2] = s.z; v[4 * k + 3] = s.w;
    }
    const u32 base = 4u * (u32)lane;
    u32 used = 0;
    for (int e = 0; e < TK; ++e) {
        u64 best = ~0ull;
        u32 bs = 0;
#pragma unroll
        for (int s = 0; s < 32; ++s) {
            u32 hb = ((used >> s) & 1u) ? 0xFFFFFFFFu : __float_as_uint(v[s]);
            u32 gidx = (u32)((s >> 2) * 256) + base + (u32)(s & 3);
            u64 key = ((u64)hb << 32) | gidx;
            if (key < best) { best = key; bs = (u32)s; }
        }
        u64 g = wave_min_u64(best);
        if (best == g) used |= (1u << bs);   // unique winner (idx in key)
        if (lane == 0) toplist[t * TK + e] = g;
    }
}

// cold path: exact masked argmin over the full cost row (first-occurrence)
__device__ void fallback_pick(const float* __restrict__ row, u32 m, int lane,
                              u32* pickIdx, float* pickVal) {
    u64 best = ~0ull;
#pragma unroll 1
    for (int k = 0; k < 8; ++k) {
        float4 q = *(const float4*)(row + k * 256 + 4 * lane);
        float vv[4] = {q.x, q.y, q.z, q.w};
#pragma unroll
        for (int e = 0; e < 4; ++e) {
            u32 gidx = (u32)(k * 256 + 4 * lane + e);
            int w = __builtin_amdgcn_ds_bpermute((int)((gidx >> 5) << 2), (int)m);
            bool taken = (((u32)w >> (gidx & 31)) & 1u) != 0u;
            u32 hb = taken ? 0xFFFFFFFFu : __float_as_uint(vv[e]);
            u64 key = ((u64)hb << 32) | gidx;
            if (key < best) best = key;
        }
    }
    best = wave_min_u64(best);
    *pickIdx = (u32)best & (NP - 1);
    *pickVal = __uint_as_float((u32)(best >> 32));
}

// K3: serial greedy, one wave. Lane = g*8+c: row-in-batch g (0..7), rank c
// (0..7). Availability word A (64-bit SGPR) computed once per batch; per pick:
// s_and byte-select -> s_ff1 -> readlane idx/val -> ballot dup-clear. Next
// batch's toplist load + bpermute issued before resolution; repaired after.
__global__ __launch_bounds__(64) void greedy_kernel(const u64* __restrict__ toplist,
                                                    const float* __restrict__ cost,
                                                    float* __restrict__ out) {
    const int lane = threadIdx.x;
    const int g = lane >> 3;
    const int c = lane & 7;
    u32 m = 0;
    float sum = 0.f;

    u64 cur = toplist[g * TK + c];
    u32 idx = (u32)cur & (NP - 1);
    u32 vb = (u32)(cur >> 32);
    u64 A = ~0ull;

    for (int t0 = 0; t0 < NT; t0 += RB) {
        const bool have_next = (t0 + RB < NT);
        u32 idxn = 0, vbn = 0;
        int wn = 0;
        if (have_next) {
            u64 nk = toplist[(t0 + RB + g) * TK + c];
            idxn = (u32)nk & (NP - 1);
            vbn = (u32)(nk >> 32);
            wn = __builtin_amdgcn_ds_bpermute((int)((idxn >> 5) << 2), (int)m);
        }

        u32 pk[RB];
#pragma unroll
        for (int gg = 0; gg < RB; ++gg) {
            u64 bal = A & (0xFFull << (8 * gg));
            u32 pickIdx; float pickVal;
            if (bal != 0) {                          // uniform branch
                int f = (int)__ffsll(bal) - 1;       // lowest lane = lowest rank
                pickIdx = (u32)__builtin_amdgcn_readlane((int)idx, f);
                pickVal = __uint_as_float((u32)__builtin_amdgcn_readlane((int)vb, f));
            } else {
                fallback_pick(cost + (size_t)(t0 + gg) * NP, m, lane,
                              &pickIdx, &pickVal);
            }
            pk[gg] = pickIdx;
            sum += pickVal;
            if ((pickIdx >> 5) == (u32)lane) m |= (1u << (pickIdx & 31));
            A &= ~__ballot(idx == pickIdx);          // clear pick + in-batch dups
        }

        if (have_next) {
            u64 An = __ballot((((u32)wn >> (idxn & 31)) & 1u) == 0u);
#pragma unroll
            for (int gg = 0; gg < RB; ++gg)
                An &= ~__ballot(idxn == pk[gg]);
            A = An;
            idx = idxn;
            vb = vbn;
        }
    }
    if (lane == 0) out[0] = sum * (1.f / NT);
}

extern "C" void kernel_launch(void* const* d_in, const int* in_sizes, int n_in,
                              void* d_out, int out_size, void* d_ws, size_t ws_size,
                              hipStream_t stream) {
    const float4* pred = (const float4*)d_in[0];
    const float* tgt = (const float*)d_in[1];
    char* ws = (char*)d_ws;
    float* cost    = (float*)ws;                                  // 2 MB
    float* partial = (float*)(ws + (size_t)NT * NP * 4);          // 8 MB
    u64* toplist   = (u64*)(ws + (size_t)NT * NP * 4 * (1 + NZ)); // 16 KB

    cost_kernel<<<dim3(NP / 256, NT / 4, NZ), 256, 0, stream>>>(pred, tgt, partial);
    topk_kernel<<<NT, 64, 0, stream>>>(partial, cost, toplist);
    greedy_kernel<<<1, 64, 0, stream>>>(toplist, cost, (float*)d_out);
}

// Round 7
// 62.123 us; speedup vs baseline: 3.2643x; 1.1208x over previous
//
#include <hip/hip_runtime.h>
#include <hip/hip_bf16.h>

typedef unsigned long long u64;
typedef unsigned int u32;

#define NB 64
#define NP 2048
#define NT 256
#define TK 8        // sorted top-K kept per row
#define RB 8        // rows resolved per greedy batch (RB*TK = 64 lanes)
#define NZ 4        // batch-dimension split of cost kernel
#define BZ (NB / NZ)
#define EPSF 1e-7f

// K1: partial[z][t][p] = sum_{b in chunk z} (1 - iou(pred[b][p], tgt[b][t]))
// grid (8, 64, 4) = 2048 blocks; b-unroll 8 -> 8 float4 loads in flight.
__global__ __launch_bounds__(256) void cost_kernel(const float4* __restrict__ pred,
                                                   const float* __restrict__ tgt,
                                                   float* __restrict__ partial) {
    const int tid = threadIdx.x;
    const int t0 = blockIdx.y * 4;
    const int z = blockIdx.z;
    const int p = blockIdx.x * 256 + tid;

    float acc[4] = {0.f, 0.f, 0.f, 0.f};

    for (int b = z * BZ; b < z * BZ + BZ; b += 8) {
        float4 pb[8];
#pragma unroll
        for (int u = 0; u < 8; ++u) pb[u] = pred[(b + u) * NP + p];
#pragma unroll
        for (int u = 0; u < 8; ++u) {
            float ap = (pb[u].z - pb[u].x) * (pb[u].w - pb[u].y);
            const float* tb = &tgt[((b + u) * NT + t0) * 4];  // uniform -> s_load
#pragma unroll
            for (int tt = 0; tt < 4; ++tt) {
                float tx1 = tb[4 * tt + 0], ty1 = tb[4 * tt + 1];
                float tx2 = tb[4 * tt + 2], ty2 = tb[4 * tt + 3];
                float at = (tx2 - tx1) * (ty2 - ty1);
                float ix1 = fmaxf(pb[u].x, tx1);
                float iy1 = fmaxf(pb[u].y, ty1);
                float ix2 = fminf(pb[u].z, tx2);
                float iy2 = fminf(pb[u].w, ty2);
                float dx = fmaxf(ix2 - ix1, 0.f);
                float dy = fmaxf(iy2 - iy1, 0.f);
                float inter = dx * dy;
                float uni = ap + at - inter + EPSF;
                acc[tt] += (1.f - inter * __builtin_amdgcn_rcpf(uni));
            }
        }
    }
#pragma unroll
    for (int tt = 0; tt < 4; ++tt)
        partial[((size_t)z * NT + t0 + tt) * NP + p] = acc[tt];
}

__device__ inline u64 wave_min_u64(u64 k) {
#pragma unroll
    for (int off = 1; off < 64; off <<= 1) {
        u32 lo = (u32)__shfl_xor((int)(u32)k, off);
        u32 hi = (u32)__shfl_xor((int)(u32)(k >> 32), off);
        u64 o = ((u64)hi << 32) | lo;
        if (o < k) k = o;
    }
    return k;  // uniform across lanes
}

// K2: fused 4-way partial reduce + cost-row write + sorted top-8 extraction.
__global__ __launch_bounds__(64) void topk_kernel(const float* __restrict__ partial,
                                                  float* __restrict__ cost,
                                                  u64* __restrict__ toplist) {
    const int lane = threadIdx.x;
    const int t = blockIdx.x;
    const float* r0 = partial + ((size_t)0 * NT + t) * NP;
    const float* r1 = partial + ((size_t)1 * NT + t) * NP;
    const float* r2 = partial + ((size_t)2 * NT + t) * NP;
    const float* r3 = partial + ((size_t)3 * NT + t) * NP;
    float* crow = cost + (size_t)t * NP;

    float v[32];
#pragma unroll
    for (int k = 0; k < 8; ++k) {
        const int off = k * 256 + 4 * lane;
        float4 a = *(const float4*)(r0 + off);
        float4 b = *(const float4*)(r1 + off);
        float4 c = *(const float4*)(r2 + off);
        float4 d = *(const float4*)(r3 + off);
        float4 s;
        s.x = (a.x + b.x + c.x + d.x) * (1.f / NB);
        s.y = (a.y + b.y + c.y + d.y) * (1.f / NB);
        s.z = (a.z + b.z + c.z + d.z) * (1.f / NB);
        s.w = (a.w + b.w + c.w + d.w) * (1.f / NB);
        *(float4*)(crow + off) = s;   // greedy fallback reads this
        v[4 * k + 0] = s.x; v[4 * k + 1] = s.y;
        v[4 * k + 2] = s.z; v[4 * k + 3] = s.w;
    }
    const u32 base = 4u * (u32)lane;
    u32 used = 0;
    for (int e = 0; e < TK; ++e) {
        u64 best = ~0ull;
        u32 bs = 0;
#pragma unroll
        for (int s = 0; s < 32; ++s) {
            u32 hb = ((used >> s) & 1u) ? 0xFFFFFFFFu : __float_as_uint(v[s]);
            u32 gidx = (u32)((s >> 2) * 256) + base + (u32)(s & 3);
            u64 key = ((u64)hb << 32) | gidx;
            if (key < best) { best = key; bs = (u32)s; }
        }
        u64 g = wave_min_u64(best);
        if (best == g) used |= (1u << bs);   // unique winner (idx in key)
        if (lane == 0) toplist[t * TK + e] = g;
    }
}

// cold path: exact masked argmin over the full cost row (first-occurrence)
__device__ void fallback_pick(const float* __restrict__ row, u32 m, int lane,
                              u32* pickIdx, float* pickVal) {
    u64 best = ~0ull;
#pragma unroll 1
    for (int k = 0; k < 8; ++k) {
        float4 q = *(const float4*)(row + k * 256 + 4 * lane);
        float vv[4] = {q.x, q.y, q.z, q.w};
#pragma unroll
        for (int e = 0; e < 4; ++e) {
            u32 gidx = (u32)(k * 256 + 4 * lane + e);
            int w = __builtin_amdgcn_ds_bpermute((int)((gidx >> 5) << 2), (int)m);
            bool taken = (((u32)w >> (gidx & 31)) & 1u) != 0u;
            u32 hb = taken ? 0xFFFFFFFFu : __float_as_uint(vv[e]);
            u64 key = ((u64)hb << 32) | gidx;
            if (key < best) best = key;
        }
    }
    best = wave_min_u64(best);
    *pickIdx = (u32)best & (NP - 1);
    *pickVal = __uint_as_float((u32)(best >> 32));
}

// K3: serial greedy, one wave, toplist fully register-resident.
// reg[k] holds toplist[64k + lane]: batch k, row 8k+g, rank c (lane = g*8+c).
// All 32 loads issued up front (one latency drain); per batch only a bpermute
// (issued during previous batch's scalar resolution) + 8 SGPR picks.
__global__ __launch_bounds__(64) void greedy_kernel(const u64* __restrict__ toplist,
                                                    const float* __restrict__ cost,
                                                    float* __restrict__ out) {
    const int lane = threadIdx.x;
    u32 idxr[32], vbr[32];
#pragma unroll
    for (int k = 0; k < 32; ++k) {
        u64 v = toplist[64 * k + lane];
        idxr[k] = (u32)v & (NP - 1);
        vbr[k] = (u32)(v >> 32);
    }

    u32 m = 0;
    float sum = 0.f;
    u64 A = ~0ull;   // batch 0: nothing masked yet

#pragma unroll
    for (int k = 0; k < 32; ++k) {
        const u32 idx = idxr[k];
        const u32 vb = vbr[k];
        // prefetch next batch's mask word under pre-batch m (repaired below);
        // LDS-latency only, overlaps this batch's scalar resolution.
        int wn = 0;
        if (k < 31)
            wn = __builtin_amdgcn_ds_bpermute((int)((idxr[k + 1] >> 5) << 2), (int)m);

        u32 pk[RB];
#pragma unroll
        for (int gg = 0; gg < RB; ++gg) {
            u64 bal = A & (0xFFull << (8 * gg));
            u32 pickIdx; float pickVal;
            if (bal != 0) {                          // uniform branch
                int f = (int)__ffsll(bal) - 1;       // lowest lane = lowest rank
                pickIdx = (u32)__builtin_amdgcn_readlane((int)idx, f);
                pickVal = __uint_as_float((u32)__builtin_amdgcn_readlane((int)vb, f));
            } else {
                fallback_pick(cost + (size_t)(k * RB + gg) * NP, m, lane,
                              &pickIdx, &pickVal);
            }
            pk[gg] = pickIdx;
            sum += pickVal;
            if ((pickIdx >> 5) == (u32)lane) m |= (1u << (pickIdx & 31));
            A &= ~__ballot(idx == pickIdx);          // clear pick + in-batch dups
        }

        if (k < 31) {
            const u32 idn = idxr[k + 1];
            u64 An = __ballot((((u32)wn >> (idn & 31)) & 1u) == 0u);
#pragma unroll
            for (int gg = 0; gg < RB; ++gg)
                An &= ~__ballot(idn == pk[gg]);
            A = An;
        }
    }
    if (lane == 0) out[0] = sum * (1.f / NT);
}

extern "C" void kernel_launch(void* const* d_in, const int* in_sizes, int n_in,
                              void* d_out, int out_size, void* d_ws, size_t ws_size,
                              hipStream_t stream) {
    const float4* pred = (const float4*)d_in[0];
    const float* tgt = (const float*)d_in[1];
    char* ws = (char*)d_ws;
    float* cost    = (float*)ws;                                  // 2 MB
    float* partial = (float*)(ws + (size_t)NT * NP * 4);          // 8 MB
    u64* toplist   = (u64*)(ws + (size_t)NT * NP * 4 * (1 + NZ)); // 16 KB

    cost_kernel<<<dim3(NP / 256, NT / 4, NZ), 256, 0, stream>>>(pred, tgt, partial);
    topk_kernel<<<NT, 64, 0, stream>>>(partial, cost, toplist);
    greedy_kernel<<<1, 64, 0, stream>>>(toplist, cost, (float*)d_out);
}

// Round 8
// 62.058 us; speedup vs baseline: 3.2677x; 1.0010x over previous
//
#include <hip/hip_runtime.h>
#include <hip/hip_bf16.h>

typedef unsigned long long u64;
typedef unsigned int u32;

#define NB 64
#define NP 2048
#define NT 256
#define TK 8        // sorted top-K kept per row
#define RB 8        // rows resolved per greedy batch (RB*TK = 64 lanes)
#define NZ 8        // batch-dimension split of cost kernel
#define BZ (NB / NZ)
#define TT 8        // targets per block
#define EPSF 1e-7f

// K1: partial[z][t][p] = sum_{b in chunk z} iou(pred[b][p], tgt[b][t])
// grid (8, 32, 8) = 2048 blocks, 8/CU. at+eps in LDS (broadcast ds_read);
// fmac accumulation; pred load reused over 8 targets.
__global__ __launch_bounds__(256) void cost_kernel(const float4* __restrict__ pred,
                                                   const float* __restrict__ tgt,
                                                   float* __restrict__ partial) {
    __shared__ float sAt[BZ][TT];   // area_t + eps, wave-uniform broadcast reads
    const int tid = threadIdx.x;
    const int t0 = blockIdx.y * TT;
    const int z = blockIdx.z;
    const int p = blockIdx.x * 256 + tid;

    if (tid < BZ * TT) {
        int b = tid >> 3, tt = tid & 7;
        float4 tb = *(const float4*)&tgt[((z * BZ + b) * NT + t0 + tt) * 4];
        sAt[b][tt] = (tb.z - tb.x) * (tb.w - tb.y) + EPSF;
    }
    __syncthreads();

    float acc[TT] = {0.f, 0.f, 0.f, 0.f, 0.f, 0.f, 0.f, 0.f};

    for (int bo = 0; bo < BZ; bo += 4) {
        float4 pb[4];
#pragma unroll
        for (int u = 0; u < 4; ++u)
            pb[u] = pred[(z * BZ + bo + u) * NP + p];
#pragma unroll
        for (int u = 0; u < 4; ++u) {
            const int b = bo + u;
            float ap = (pb[u].z - pb[u].x) * (pb[u].w - pb[u].y);
            const float* tb = &tgt[((z * BZ + b) * NT + t0) * 4];  // uniform -> s_load
#pragma unroll
            for (int tt = 0; tt < TT; ++tt) {
                float tx1 = tb[4 * tt + 0], ty1 = tb[4 * tt + 1];
                float tx2 = tb[4 * tt + 2], ty2 = tb[4 * tt + 3];
                float ix1 = fmaxf(pb[u].x, tx1);
                float iy1 = fmaxf(pb[u].y, ty1);
                float ix2 = fminf(pb[u].z, tx2);
                float iy2 = fminf(pb[u].w, ty2);
                float dx = fmaxf(ix2 - ix1, 0.f);
                float dy = fmaxf(iy2 - iy1, 0.f);
                float inter = dx * dy;
                float uni = (ap + sAt[b][tt]) - inter;   // at+eps from LDS
                acc[tt] += inter * __builtin_amdgcn_rcpf(uni);  // v_fmac
            }
        }
    }
#pragma unroll
    for (int tt = 0; tt < TT; ++tt)
        partial[((size_t)z * NT + t0 + tt) * NP + p] = acc[tt];
}

__device__ inline u64 wave_min_u64(u64 k) {
#pragma unroll
    for (int off = 1; off < 64; off <<= 1) {
        u32 lo = (u32)__shfl_xor((int)(u32)k, off);
        u32 hi = (u32)__shfl_xor((int)(u32)(k >> 32), off);
        u64 o = ((u64)hi << 32) | lo;
        if (o < k) k = o;
    }
    return k;  // uniform across lanes
}

// K2: fused 8-way partial reduce (cost = 1 - sum/NB) + cost-row write +
// sorted top-8 extraction on packed (valbits<<32 | idx) keys.
__global__ __launch_bounds__(64) void topk_kernel(const float* __restrict__ partial,
                                                  float* __restrict__ cost,
                                                  u64* __restrict__ toplist) {
    const int lane = threadIdx.x;
    const int t = blockIdx.x;
    float* crow = cost + (size_t)t * NP;

    float v[32];
#pragma unroll
    for (int k = 0; k < 8; ++k) {
        const int off = k * 256 + 4 * lane;
        float4 s = {0.f, 0.f, 0.f, 0.f};
#pragma unroll
        for (int z = 0; z < NZ; ++z) {
            float4 a = *(const float4*)(partial + ((size_t)z * NT + t) * NP + off);
            s.x += a.x; s.y += a.y; s.z += a.z; s.w += a.w;
        }
        float4 c;
        c.x = 1.f - s.x * (1.f / NB);
        c.y = 1.f - s.y * (1.f / NB);
        c.z = 1.f - s.z * (1.f / NB);
        c.w = 1.f - s.w * (1.f / NB);
        *(float4*)(crow + off) = c;   // greedy fallback reads this
        v[4 * k + 0] = c.x; v[4 * k + 1] = c.y;
        v[4 * k + 2] = c.z; v[4 * k + 3] = c.w;
    }
    const u32 base = 4u * (u32)lane;
    u32 used = 0;
    for (int e = 0; e < TK; ++e) {
        u64 best = ~0ull;
        u32 bs = 0;
#pragma unroll
        for (int s = 0; s < 32; ++s) {
            u32 hb = ((used >> s) & 1u) ? 0xFFFFFFFFu : __float_as_uint(v[s]);
            u32 gidx = (u32)((s >> 2) * 256) + base + (u32)(s & 3);
            u64 key = ((u64)hb << 32) | gidx;
            if (key < best) { best = key; bs = (u32)s; }
        }
        u64 g = wave_min_u64(best);
        if (best == g) used |= (1u << bs);   // unique winner (idx in key)
        if (lane == 0) toplist[t * TK + e] = g;
    }
}

// cold path: exact masked argmin over the full cost row (first-occurrence)
__device__ void fallback_pick(const float* __restrict__ row, u32 m, int lane,
                              u32* pickIdx, float* pickVal) {
    u64 best = ~0ull;
#pragma unroll 1
    for (int k = 0; k < 8; ++k) {
        float4 q = *(const float4*)(row + k * 256 + 4 * lane);
        float vv[4] = {q.x, q.y, q.z, q.w};
#pragma unroll
        for (int e = 0; e < 4; ++e) {
            u32 gidx = (u32)(k * 256 + 4 * lane + e);
            int w = __builtin_amdgcn_ds_bpermute((int)((gidx >> 5) << 2), (int)m);
            bool taken = (((u32)w >> (gidx & 31)) & 1u) != 0u;
            u32 hb = taken ? 0xFFFFFFFFu : __float_as_uint(vv[e]);
            u64 key = ((u64)hb << 32) | gidx;
            if (key < best) best = key;
        }
    }
    best = wave_min_u64(best);
    *pickIdx = (u32)best & (NP - 1);
    *pickVal = __uint_as_float((u32)(best >> 32));
}

// K3: serial greedy, one wave, toplist fully register-resident (validated).
__global__ __launch_bounds__(64) void greedy_kernel(const u64* __restrict__ toplist,
                                                    const float* __restrict__ cost,
                                                    float* __restrict__ out) {
    const int lane = threadIdx.x;
    u32 idxr[32], vbr[32];
#pragma unroll
    for (int k = 0; k < 32; ++k) {
        u64 v = toplist[64 * k + lane];
        idxr[k] = (u32)v & (NP - 1);
        vbr[k] = (u32)(v >> 32);
    }

    u32 m = 0;
    float sum = 0.f;
    u64 A = ~0ull;   // batch 0: nothing masked yet

#pragma unroll
    for (int k = 0; k < 32; ++k) {
        const u32 idx = idxr[k];
        const u32 vb = vbr[k];
        int wn = 0;
        if (k < 31)
            wn = __builtin_amdgcn_ds_bpermute((int)((idxr[k + 1] >> 5) << 2), (int)m);

        u32 pk[RB];
#pragma unroll
        for (int gg = 0; gg < RB; ++gg) {
            u64 bal = A & (0xFFull << (8 * gg));
            u32 pickIdx; float pickVal;
            if (bal != 0) {                          // uniform branch
                int f = (int)__ffsll(bal) - 1;       // lowest lane = lowest rank
                pickIdx = (u32)__builtin_amdgcn_readlane((int)idx, f);
                pickVal = __uint_as_float((u32)__builtin_amdgcn_readlane((int)vb, f));
            } else {
                fallback_pick(cost + (size_t)(k * RB + gg) * NP, m, lane,
                              &pickIdx, &pickVal);
            }
            pk[gg] = pickIdx;
            sum += pickVal;
            if ((pickIdx >> 5) == (u32)lane) m |= (1u << (pickIdx & 31));
            A &= ~__ballot(idx == pickIdx);          // clear pick + in-batch dups
        }

        if (k < 31) {
            const u32 idn = idxr[k + 1];
            u64 An = __ballot((((u32)wn >> (idn & 31)) & 1u) == 0u);
#pragma unroll
            for (int gg = 0; gg < RB; ++gg)
                An &= ~__ballot(idn == pk[gg]);
            A = An;
        }
    }
    if (lane == 0) out[0] = sum * (1.f / NT);
}

extern "C" void kernel_launch(void* const* d_in, const int* in_sizes, int n_in,
                              void* d_out, int out_size, void* d_ws, size_t ws_size,
                              hipStream_t stream) {
    const float4* pred = (const float4*)d_in[0];
    const float* tgt = (const float*)d_in[1];
    char* ws = (char*)d_ws;
    float* cost    = (float*)ws;                                   // 2 MB
    float* partial = (float*)(ws + (size_t)NT * NP * 4);           // 16 MB
    u64* toplist   = (u64*)(ws + (size_t)NT * NP * 4 * (1 + NZ));  // 16 KB

    cost_kernel<<<dim3(NP / 256, NT / TT, NZ), 256, 0, stream>>>(pred, tgt, partial);
    topk_kernel<<<NT, 64, 0, stream>>>(partial, cost, toplist);
    greedy_kernel<<<1, 64, 0, stream>>>(toplist, cost, (float*)d_out);
}